// Round 6
// baseline (350.611 us; speedup 1.0000x reference)
//
#include <hip/hip_runtime.h>
#include <hip/hip_cooperative_groups.h>
#include <math.h>

namespace cg = cooperative_groups;

#define NN 5000      // nodes
#define NE 40000     // edges
#define UU 64        // hidden units
#define FE 16        // edge features
#define FEP 17       // +1 pseudo-feature for edge_bias
#define KD (FEP*UU)  // 1088
#define LDK (KD+8)   // padded LDS row (halfs); stride 548 dw == 4 mod 32
#define NSTEPS 4
#define NT 16        // nodes per tile
#define NTILES 313   // ceil(5000/16)
#define GRID 256     // 1 block/CU, co-resident (cooperative)
#define EMAX 1024    // max edges per 16-node tile (mean 128)
#define CH 8         // gather pipeline chunk
#define WBN (UU*KD)  // 69632
#define GTN (192*64) // 12288

typedef _Float16 half8 __attribute__((ext_vector_type(8)));
typedef float f32x4 __attribute__((ext_vector_type(4)));

__device__ __forceinline__ float sigm(float x){ return 1.f/(1.f + __expf(-x)); }
__device__ __forceinline__ int rfl(int x){ return __builtin_amdgcn_readfirstlane(x); }

__global__ __launch_bounds__(512, 2) void mega_k(
    const float* __restrict__ nodef, const float* __restrict__ edgef,
    const int* __restrict__ pair,   const float* __restrict__ ek,
    const float* __restrict__ eb,   const float* __restrict__ gk,
    const float* __restrict__ rk,   const float* __restrict__ gb,
    int* __restrict__ offs, int* __restrict__ cursor, int* __restrict__ eid,
    _Float16* __restrict__ wb, _Float16* __restrict__ gkt, _Float16* __restrict__ rkt,
    float* __restrict__ hA, float* __restrict__ hB, float* __restrict__ dout){

  __shared__ _Float16 Gs[NT*LDK];      // 35072 B (also reused as scan scratch)
  __shared__ int      enbr[EMAX];      // 4096 B
  __shared__ int      eedg[EMAX];      // 4096 B
  __shared__ _Float16 aggT[NT*72];     // 2304 B
  __shared__ _Float16 hT[NT*72];       // 2304 B

  cg::grid_group grid = cg::this_grid();
  int tid = threadIdx.x;
  int gt  = blockIdx.x*512 + tid;      // 0..131071
  int w = tid >> 6, lane = tid & 63;
  int r16 = lane & 15, kh = lane >> 4;

  // ---- P0: build f16 weight tables + zero offs ----
  if (gt <= NN) offs[gt] = 0;
  if (gt < WBN){
    int i = gt / KD, k = gt - i*KD;
    int f = k >> 6, j = k & 63;
    float v = (f < FE) ? ek[f*4096 + i*64 + j] : eb[i*64 + j];
    wb[gt] = (_Float16)v;
  } else if (gt < WBN + GTN){
    int r = gt - WBN; int n = r >> 6, k = r & 63;
    gkt[r] = (_Float16)gk[k*192 + n];
  } else if (gt < WBN + 2*GTN){
    int r = gt - WBN - GTN; int n = r >> 6, k = r & 63;
    rkt[r] = (_Float16)rk[k*192 + n];
  }
  grid.sync();

  // ---- P1: histogram (int atomics, order-independent) ----
  if (gt < NE) atomicAdd(&offs[pair[2*gt]], 1);
  grid.sync();

  // ---- P2: exclusive scan (block 0 only, 512 threads, PER=10) ----
  if (blockIdx.x == 0){
    int* sArr = (int*)Gs;
    const int PER = 10;                // 512*10 = 5120 >= 5001
    int base = tid*PER;
    int loc[PER]; int sum = 0;
    #pragma unroll
    for (int q=0;q<PER;++q){ int idx=base+q; int v=(idx<NN)?offs[idx]:0; loc[q]=v; sum+=v; }
    sArr[tid] = sum; __syncthreads();
    for (int off=1; off<512; off<<=1){
      int v = (tid>=off) ? sArr[tid-off] : 0;
      __syncthreads();
      sArr[tid] += v;
      __syncthreads();
    }
    int run = sArr[tid] - sum;
    #pragma unroll
    for (int q=0;q<PER;++q){ int idx=base+q;
      if (idx<NN){ offs[idx]=run; cursor[idx]=run; run+=loc[q]; } }
    if (tid==511) offs[NN] = NE;
  }
  grid.sync();

  // ---- P3: scatter (atomic slot alloc; order canonicalized by sort below) ----
  if (gt < NE){ int pos = atomicAdd(&cursor[pair[2*gt]], 1); eid[pos] = gt; }
  grid.sync();

  // ---- P4..P7: message-passing steps (sort folded into step 0) ----
  for (int s=0; s<NSTEPS; ++s){
    const float* h_in  = (s==0) ? nodef : ((s&1) ? hA : hB);
    float*       h_out = (s==NSTEPS-1) ? dout : ((s&1) ? hB : hA);

    for (int t = blockIdx.x; t < NTILES; t += GRID){
      int vb = t * NT;
      int vtop = (vb + NT < NN) ? vb + NT : NN;

      if (s == 0){
        // canonical per-node order: insertion-sort this tile's sublists
        if (tid < NT && vb + tid < NN){
          int b = offs[vb+tid], e = offs[vb+tid+1];
          for (int i=b+1; i<e; ++i){
            int key = eid[i]; int j = i-1;
            while (j>=b && eid[j]>key){ eid[j+1]=eid[j]; --j; }
            eid[j+1] = key;
          }
        }
        __syncthreads();
      }

      int ebase = offs[vb];
      int ecnt  = offs[vtop] - ebase;

      // stage neighbor/edge ids + own h tile (f16)
      for (int i=tid; i<ecnt; i+=512){
        int e = eid[ebase + i];
        enbr[i] = pair[2*e + 1];
        eedg[i] = e;
      }
      for (int i=tid; i<NT*64; i+=512){
        int lv = i >> 6, j = i & 63; int v = vb + lv;
        hT[lv*72 + j] = (_Float16)((v < NN) ? h_in[(size_t)v*64 + j] : 0.f);
      }
      __syncthreads();

      // gather: wave w owns nodes vb+2w, vb+2w+1 (17 features, lane = unit)
      #pragma unroll
      for (int nn=0; nn<2; ++nn){
        int node = vb + w*2 + nn;
        if (node < NN){
          int myb = offs[node]   - ebase;
          int mye = offs[node+1] - ebase;
          float g[FEP];
          #pragma unroll
          for (int f=0;f<FEP;++f) g[f] = 0.f;
          for (int c0=myb; c0<mye; c0+=CH){
            float hj[CH];
            #pragma unroll
            for (int q=0;q<CH;++q){ int i=c0+q;
              if (i<mye){ int nb = rfl(enbr[i]); hj[q] = h_in[(size_t)nb*64 + lane]; }
              else hj[q] = 0.f; }
            #pragma unroll
            for (int q=0;q<CH;++q){ int i=c0+q;
              if (i<mye){
                int e = rfl(eedg[i]);
                const float4* er = (const float4*)(edgef + (size_t)e*FE);
                float4 e0 = er[0], e1 = er[1], e2 = er[2], e3 = er[3];
                g[ 0]=fmaf(e0.x,hj[q],g[ 0]); g[ 1]=fmaf(e0.y,hj[q],g[ 1]);
                g[ 2]=fmaf(e0.z,hj[q],g[ 2]); g[ 3]=fmaf(e0.w,hj[q],g[ 3]);
                g[ 4]=fmaf(e1.x,hj[q],g[ 4]); g[ 5]=fmaf(e1.y,hj[q],g[ 5]);
                g[ 6]=fmaf(e1.z,hj[q],g[ 6]); g[ 7]=fmaf(e1.w,hj[q],g[ 7]);
                g[ 8]=fmaf(e2.x,hj[q],g[ 8]); g[ 9]=fmaf(e2.y,hj[q],g[ 9]);
                g[10]=fmaf(e2.z,hj[q],g[10]); g[11]=fmaf(e2.w,hj[q],g[11]);
                g[12]=fmaf(e3.x,hj[q],g[12]); g[13]=fmaf(e3.y,hj[q],g[13]);
                g[14]=fmaf(e3.z,hj[q],g[14]); g[15]=fmaf(e3.w,hj[q],g[15]);
                g[16] += hj[q];
              } }
          }
          #pragma unroll
          for (int f=0;f<FEP;++f) Gs[(w*2+nn)*LDK + f*64 + lane] = (_Float16)g[f];
        }
      }
      __syncthreads();

      // agg matmul: waves 0-3, wave w = cols w*16..w*16+15; all 16 A rows valid
      if (w < 4){
        f32x4 acc = {0.f,0.f,0.f,0.f};
        const _Float16* ap = Gs + r16*LDK + kh*8;
        const _Float16* bp = wb + (size_t)(w*16 + r16)*KD + kh*8;
        #pragma unroll 2
        for (int k0=0; k0<KD; k0+=32){
          half8 a = *(const half8*)(ap + k0);
          half8 b = *(const half8*)(bp + k0);
          acc = __builtin_amdgcn_mfma_f32_16x16x32_f16(a, b, acc, 0, 0, 0);
        }
        #pragma unroll
        for (int r=0;r<4;++r) aggT[(kh*4+r)*72 + w*16 + r16] = (_Float16)acc[r];
      }
      __syncthreads();

      // GRU via MFMA: waves 0-3, wave w owns units uw = w*16 + r16
      if (w < 4){
        int uw = w*16 + r16;
        const _Float16* az = aggT + r16*72 + kh*8;
        const _Float16* ah = hT   + r16*72 + kh*8;
        f32x4 mxz={0.f,0.f,0.f,0.f}, mxr=mxz, mxh=mxz, mhz=mxz, mhr=mxz, mhh=mxz;
        #pragma unroll
        for (int ks=0; ks<2; ++ks){
          half8 aa = *(const half8*)(az + ks*32);
          half8 hh = *(const half8*)(ah + ks*32);
          half8 bz = *(const half8*)(gkt + (size_t)(      uw)*64 + ks*32 + kh*8);
          half8 br = *(const half8*)(gkt + (size_t)( 64 + uw)*64 + ks*32 + kh*8);
          half8 bh = *(const half8*)(gkt + (size_t)(128 + uw)*64 + ks*32 + kh*8);
          half8 cz = *(const half8*)(rkt + (size_t)(      uw)*64 + ks*32 + kh*8);
          half8 cr = *(const half8*)(rkt + (size_t)( 64 + uw)*64 + ks*32 + kh*8);
          half8 ch = *(const half8*)(rkt + (size_t)(128 + uw)*64 + ks*32 + kh*8);
          mxz = __builtin_amdgcn_mfma_f32_16x16x32_f16(aa, bz, mxz, 0,0,0);
          mxr = __builtin_amdgcn_mfma_f32_16x16x32_f16(aa, br, mxr, 0,0,0);
          mxh = __builtin_amdgcn_mfma_f32_16x16x32_f16(aa, bh, mxh, 0,0,0);
          mhz = __builtin_amdgcn_mfma_f32_16x16x32_f16(hh, cz, mhz, 0,0,0);
          mhr = __builtin_amdgcn_mfma_f32_16x16x32_f16(hh, cr, mhr, 0,0,0);
          mhh = __builtin_amdgcn_mfma_f32_16x16x32_f16(hh, ch, mhh, 0,0,0);
        }
        float b0z = gb[uw],      b0r = gb[64+uw],  b0h = gb[128+uw];
        float b1z = gb[192+uw],  b1r = gb[256+uw], b1h = gb[320+uw];
        #pragma unroll
        for (int r=0;r<4;++r){
          int row = vb + kh*4 + r;
          if (row < NN){
            float z  = sigm(mxz[r] + b0z + mhz[r] + b1z);
            float rr = sigm(mxr[r] + b0r + mhr[r] + b1r);
            float hc = tanhf(mxh[r] + b0h + rr*(mhh[r] + b1h));
            float hold = h_in[(size_t)row*64 + uw];
            h_out[(size_t)row*64 + uw] = z*hold + (1.f - z)*hc;
          }
        }
      }
      __syncthreads();   // protect LDS before next tile overwrites
    }
    if (s < NSTEPS-1) grid.sync();
  }
}

extern "C" void kernel_launch(void* const* d_in, const int* in_sizes, int n_in,
                              void* d_out, int out_size, void* d_ws, size_t ws_size,
                              hipStream_t stream){
  const float* nodef = (const float*)d_in[0];
  const float* edgef = (const float*)d_in[1];
  const int*   pair  = (const int*)  d_in[2];
  const float* ek    = (const float*)d_in[3];
  const float* ebias = (const float*)d_in[4];
  const float* gk    = (const float*)d_in[5];
  const float* rk    = (const float*)d_in[6];
  const float* gb    = (const float*)d_in[7];
  float*       dout  = (float*)d_out;

  char* ws = (char*)d_ws;
  size_t o = 0;
  auto carve = [&](size_t bytes)->char*{
    char* p = ws + o; o = (o + bytes + 255) & ~255ULL; return p; };
  int*      offs   = (int*)     carve((NN+1)*sizeof(int));
  int*      cursor = (int*)     carve(NN*sizeof(int));
  int*      eid    = (int*)     carve(NE*sizeof(int));
  _Float16* wb     = (_Float16*)carve((size_t)WBN*sizeof(_Float16));
  _Float16* gkt    = (_Float16*)carve((size_t)GTN*sizeof(_Float16));
  _Float16* rkt    = (_Float16*)carve((size_t)GTN*sizeof(_Float16));
  float*    hA     = (float*)   carve((size_t)NN*UU*sizeof(float));
  float*    hB     = (float*)   carve((size_t)NN*UU*sizeof(float));

  void* args[] = { (void*)&nodef, (void*)&edgef, (void*)&pair, (void*)&ek,
                   (void*)&ebias, (void*)&gk, (void*)&rk, (void*)&gb,
                   (void*)&offs, (void*)&cursor, (void*)&eid,
                   (void*)&wb, (void*)&gkt, (void*)&rkt,
                   (void*)&hA, (void*)&hB, (void*)&dout };
  hipLaunchCooperativeKernel((void*)mega_k, dim3(GRID), dim3(512), args, 0, stream);
}

// Round 7
// 148.176 us; speedup vs baseline: 2.3662x; 2.3662x over previous
//
#include <hip/hip_runtime.h>
#include <math.h>

#define NN 5000      // nodes
#define NE 40000     // edges
#define UU 64        // hidden units
#define FE 16        // edge features
#define FEP 17       // +1 pseudo-feature for edge_bias
#define KD (FEP*UU)  // 1088
#define LDK (KD+8)   // padded LDS row (halfs); stride 548 dw == 4 mod 32
#define NSTEPS 4
#define NT 8         // nodes per step-tile (5000 % 8 == 0)
#define NB (NN/NT)   // 625 blocks
#define SLOT 40      // per-node edge bucket capacity (mean deg 8, P(>=40)~1e-15)
#define CH 8         // gather pipeline chunk
#define WBN (UU*KD)  // 69632
#define GTN (192*64) // 12288

typedef _Float16 half8 __attribute__((ext_vector_type(8)));
typedef float f32x4 __attribute__((ext_vector_type(4)));

__device__ __forceinline__ float sigm(float x){ return 1.f/(1.f + __expf(-x)); }
__device__ __forceinline__ int rfl(int x){ return __builtin_amdgcn_readfirstlane(x); }

// ---- build f16 weight tables + zero per-node degree counters ----
__global__ void build_k(const float* __restrict__ ek, const float* __restrict__ eb,
                        const float* __restrict__ gk, const float* __restrict__ rk,
                        _Float16* __restrict__ wb, _Float16* __restrict__ gkt,
                        _Float16* __restrict__ rkt, int* __restrict__ deg){
  int tid = blockIdx.x*blockDim.x + threadIdx.x;
  if (tid < NN) deg[tid] = 0;
  if (tid < WBN){
    int i = tid / KD, k = tid - i*KD;
    int f = k >> 6, j = k & 63;
    float v = (f < FE) ? ek[f*4096 + i*64 + j] : eb[i*64 + j];
    wb[tid] = (_Float16)v;
  } else if (tid < WBN + GTN){
    int r = tid - WBN; int n = r >> 6, k = r & 63;
    gkt[r] = (_Float16)gk[k*192 + n];
  } else if (tid < WBN + 2*GTN){
    int r = tid - WBN - GTN; int n = r >> 6, k = r & 63;
    rkt[r] = (_Float16)rk[k*192 + n];
  }
}

// ---- bucket edges by src (atomic slot alloc; order canonicalized in prep_k) ----
__global__ void bucket_k(const int* __restrict__ pair, int* __restrict__ deg,
                         int* __restrict__ eidb){
  int e = blockIdx.x*blockDim.x + threadIdx.x;
  if (e < NE){
    int v = pair[2*e];
    int pos = atomicAdd(&deg[v], 1);
    if (pos < SLOT) eidb[v*SLOT + pos] = e;
  }
}

// ---- canonical order (sort by edge id) + pre-resolve (e, nbr) pairs ----
__global__ void prep_k(const int* __restrict__ pair, const int* __restrict__ deg,
                       int* __restrict__ eidb, int2* __restrict__ enb){
  int v = blockIdx.x*blockDim.x + threadIdx.x;
  if (v >= NN) return;
  int dg = deg[v]; if (dg > SLOT) dg = SLOT;
  int* lst = eidb + v*SLOT;
  for (int i=1; i<dg; ++i){
    int key = lst[i]; int j = i-1;
    while (j>=0 && lst[j]>key){ lst[j+1]=lst[j]; --j; }
    lst[j+1] = key;
  }
  for (int i=0; i<dg; ++i){
    int e = lst[i];
    enb[v*SLOT + i] = make_int2(e, pair[2*e + 1]);
  }
}

// ---- fused step, 8-node tile, 8 waves: gather (1 wave/node) -> MFMA agg -> MFMA GRU ----
__global__ __launch_bounds__(512) void step_k(const float* __restrict__ h_in,
        float* __restrict__ h_out, const float* __restrict__ ef,
        const int* __restrict__ deg, const int2* __restrict__ enb,
        const _Float16* __restrict__ wb, const _Float16* __restrict__ gkt,
        const _Float16* __restrict__ rkt, const float* __restrict__ gb){
  __shared__ _Float16 Gs[NT*LDK];      // 17536 B
  __shared__ _Float16 aggT[NT*72];     // 1152 B
  __shared__ _Float16 hT[NT*72];       // 1152 B

  int tid = threadIdx.x;
  int w = tid >> 6, lane = tid & 63;
  int r16 = lane & 15, kh = lane >> 4;
  int vb = blockIdx.x * NT;
  int v  = vb + w;                     // this wave's node

  hT[w*72 + lane] = (_Float16)h_in[(size_t)v*64 + lane];

  // ---- gather: wave w owns node v (17 features, lane = unit) ----
  {
    int dgv = rfl(deg[v]); if (dgv > SLOT) dgv = SLOT;
    const int2* lst = enb + v*SLOT;
    float g[FEP];
    #pragma unroll
    for (int f=0;f<FEP;++f) g[f] = 0.f;
    for (int c0=0; c0<dgv; c0+=CH){
      int ee[CH], nb[CH];
      #pragma unroll
      for (int q=0;q<CH;++q){ int i=c0+q;
        if (i<dgv){ int2 p = lst[i]; ee[q]=rfl(p.x); nb[q]=rfl(p.y); }
        else { ee[q]=0; nb[q]=0; } }
      float hj[CH];
      #pragma unroll
      for (int q=0;q<CH;++q){ int i=c0+q;
        hj[q] = (i<dgv) ? h_in[(size_t)nb[q]*64 + lane] : 0.f; }
      #pragma unroll
      for (int q=0;q<CH;++q){ int i=c0+q;
        if (i<dgv){
          const float4* er = (const float4*)(ef + (size_t)ee[q]*FE);
          float4 e0 = er[0], e1 = er[1], e2 = er[2], e3 = er[3];
          g[ 0]=fmaf(e0.x,hj[q],g[ 0]); g[ 1]=fmaf(e0.y,hj[q],g[ 1]);
          g[ 2]=fmaf(e0.z,hj[q],g[ 2]); g[ 3]=fmaf(e0.w,hj[q],g[ 3]);
          g[ 4]=fmaf(e1.x,hj[q],g[ 4]); g[ 5]=fmaf(e1.y,hj[q],g[ 5]);
          g[ 6]=fmaf(e1.z,hj[q],g[ 6]); g[ 7]=fmaf(e1.w,hj[q],g[ 7]);
          g[ 8]=fmaf(e2.x,hj[q],g[ 8]); g[ 9]=fmaf(e2.y,hj[q],g[ 9]);
          g[10]=fmaf(e2.z,hj[q],g[10]); g[11]=fmaf(e2.w,hj[q],g[11]);
          g[12]=fmaf(e3.x,hj[q],g[12]); g[13]=fmaf(e3.y,hj[q],g[13]);
          g[14]=fmaf(e3.z,hj[q],g[14]); g[15]=fmaf(e3.w,hj[q],g[15]);
          g[16] += hj[q];
        } }
    }
    #pragma unroll
    for (int f=0;f<FEP;++f) Gs[w*LDK + f*64 + lane] = (_Float16)g[f];
  }
  __syncthreads();

  // ---- agg matmul: waves 0-3, wave w = cols w*16..w*16+15; A rows 0-7 valid ----
  if (w < 4){
    f32x4 acc = {0.f,0.f,0.f,0.f};
    const _Float16* ap = Gs + (r16 & 7)*LDK + kh*8;
    const _Float16* bp = wb + (size_t)(w*16 + r16)*KD + kh*8;
    #pragma unroll 4
    for (int k0=0; k0<KD; k0+=32){
      half8 a = *(const half8*)(ap + k0);
      half8 b = *(const half8*)(bp + k0);
      acc = __builtin_amdgcn_mfma_f32_16x16x32_f16(a, b, acc, 0, 0, 0);
    }
    if (kh < 2){           // C rows 0-7 live in kh 0,1 (row = kh*4+r)
      #pragma unroll
      for (int r=0;r<4;++r) aggT[(kh*4+r)*72 + w*16 + r16] = (_Float16)acc[r];
    }
  }
  __syncthreads();

  // ---- GRU via MFMA: waves 0-3, wave w owns units uw = w*16 + r16 ----
  if (w < 4){
    int uw = w*16 + r16;
    const _Float16* az = aggT + (r16 & 7)*72 + kh*8;
    const _Float16* ah = hT   + (r16 & 7)*72 + kh*8;
    f32x4 mxz={0.f,0.f,0.f,0.f}, mxr=mxz, mxh=mxz, mhz=mxz, mhr=mxz, mhh=mxz;
    #pragma unroll
    for (int ks=0; ks<2; ++ks){
      half8 aa = *(const half8*)(az + ks*32);
      half8 hh = *(const half8*)(ah + ks*32);
      half8 bz = *(const half8*)(gkt + (size_t)(      uw)*64 + ks*32 + kh*8);
      half8 br = *(const half8*)(gkt + (size_t)( 64 + uw)*64 + ks*32 + kh*8);
      half8 bh = *(const half8*)(gkt + (size_t)(128 + uw)*64 + ks*32 + kh*8);
      half8 cz = *(const half8*)(rkt + (size_t)(      uw)*64 + ks*32 + kh*8);
      half8 cr = *(const half8*)(rkt + (size_t)( 64 + uw)*64 + ks*32 + kh*8);
      half8 ch = *(const half8*)(rkt + (size_t)(128 + uw)*64 + ks*32 + kh*8);
      mxz = __builtin_amdgcn_mfma_f32_16x16x32_f16(aa, bz, mxz, 0,0,0);
      mxr = __builtin_amdgcn_mfma_f32_16x16x32_f16(aa, br, mxr, 0,0,0);
      mxh = __builtin_amdgcn_mfma_f32_16x16x32_f16(aa, bh, mxh, 0,0,0);
      mhz = __builtin_amdgcn_mfma_f32_16x16x32_f16(hh, cz, mhz, 0,0,0);
      mhr = __builtin_amdgcn_mfma_f32_16x16x32_f16(hh, cr, mhr, 0,0,0);
      mhh = __builtin_amdgcn_mfma_f32_16x16x32_f16(hh, ch, mhh, 0,0,0);
    }
    if (kh < 2){
      float b0z = gb[uw],      b0r = gb[64+uw],  b0h = gb[128+uw];
      float b1z = gb[192+uw],  b1r = gb[256+uw], b1h = gb[320+uw];
      #pragma unroll
      for (int r=0;r<4;++r){
        int row = vb + kh*4 + r;
        float z  = sigm(mxz[r] + b0z + mhz[r] + b1z);
        float rr = sigm(mxr[r] + b0r + mhr[r] + b1r);
        float hc = tanhf(mxh[r] + b0h + rr*(mhh[r] + b1h));
        float hold = h_in[(size_t)row*64 + uw];
        h_out[(size_t)row*64 + uw] = z*hold + (1.f - z)*hc;
      }
    }
  }
}

extern "C" void kernel_launch(void* const* d_in, const int* in_sizes, int n_in,
                              void* d_out, int out_size, void* d_ws, size_t ws_size,
                              hipStream_t stream){
  const float* nodef = (const float*)d_in[0];
  const float* edgef = (const float*)d_in[1];
  const int*   pair  = (const int*)  d_in[2];
  const float* ek    = (const float*)d_in[3];
  const float* ebias = (const float*)d_in[4];
  const float* gk    = (const float*)d_in[5];
  const float* rk    = (const float*)d_in[6];
  const float* gb    = (const float*)d_in[7];

  char* ws = (char*)d_ws;
  size_t o = 0;
  auto carve = [&](size_t bytes)->char*{
    char* p = ws + o; o = (o + bytes + 255) & ~255ULL; return p; };
  int*      deg  = (int*)     carve(NN*sizeof(int));
  int*      eidb = (int*)     carve((size_t)NN*SLOT*sizeof(int));
  int2*     enb  = (int2*)    carve((size_t)NN*SLOT*sizeof(int2));
  _Float16* wb   = (_Float16*)carve((size_t)WBN*sizeof(_Float16));
  _Float16* gkt  = (_Float16*)carve((size_t)GTN*sizeof(_Float16));
  _Float16* rkt  = (_Float16*)carve((size_t)GTN*sizeof(_Float16));
  float*    hA   = (float*)   carve((size_t)NN*UU*sizeof(float));
  float*    hB   = (float*)   carve((size_t)NN*UU*sizeof(float));

  build_k <<<(WBN+2*GTN+255)/256, 256, 0, stream>>>(ek, ebias, gk, rk, wb, gkt, rkt, deg);
  bucket_k<<<(NE+255)/256, 256, 0, stream>>>(pair, deg, eidb);
  prep_k  <<<(NN+255)/256, 256, 0, stream>>>(pair, deg, eidb, enb);

  const float* hin = nodef;
  for (int s=0; s<NSTEPS; ++s){
    float* hout = (s == NSTEPS-1) ? (float*)d_out : ((s & 1) ? hB : hA);
    step_k<<<NB, 512, 0, stream>>>(hin, hout, edgef, deg, enb,
                                   wb, gkt, rkt, gb);
    hin = hout;
  }
}

// Round 8
// 115.044 us; speedup vs baseline: 3.0476x; 1.2880x over previous
//
#include <hip/hip_runtime.h>
#include <math.h>

#define NN 5000      // nodes
#define NE 40000     // edges
#define UU 64        // hidden units
#define FE 16        // edge features
#define FEP 17       // +1 pseudo-feature for edge_bias
#define KD (FEP*UU)  // 1088
#define LDK (KD+8)   // padded LDS row (halfs); stride 548 dw == 4 mod 32
#define NSTEPS 4
#define NT 8         // nodes per step-tile (5000 % 8 == 0)
#define NB (NN/NT)   // 625 blocks
#define SLOT 40      // per-node edge bucket capacity (mean deg 8, P(>=40)~1e-15)
#define CH 8         // gather pipeline chunk
#define WBN (UU*KD)  // 69632
#define GTN (192*64) // 12288

typedef _Float16 half8 __attribute__((ext_vector_type(8)));
typedef float f32x4 __attribute__((ext_vector_type(4)));

__device__ __forceinline__ float sigm(float x){ return 1.f/(1.f + __expf(-x)); }
__device__ __forceinline__ int rfl(int x){ return __builtin_amdgcn_readfirstlane(x); }

// ---- build f16 weight tables + zero per-node degree counters ----
__global__ void build_k(const float* __restrict__ ek, const float* __restrict__ eb,
                        const float* __restrict__ gk, const float* __restrict__ rk,
                        _Float16* __restrict__ wb, _Float16* __restrict__ gkt,
                        _Float16* __restrict__ rkt, int* __restrict__ deg){
  int tid = blockIdx.x*blockDim.x + threadIdx.x;
  if (tid < NN) deg[tid] = 0;
  if (tid < WBN){
    int i = tid / KD, k = tid - i*KD;
    int f = k >> 6, j = k & 63;
    float v = (f < FE) ? ek[f*4096 + i*64 + j] : eb[i*64 + j];
    wb[tid] = (_Float16)v;
  } else if (tid < WBN + GTN){
    int r = tid - WBN; int n = r >> 6, k = r & 63;
    gkt[r] = (_Float16)gk[k*192 + n];
  } else if (tid < WBN + 2*GTN){
    int r = tid - WBN - GTN; int n = r >> 6, k = r & 63;
    rkt[r] = (_Float16)rk[k*192 + n];
  }
}

// ---- bucket edges by src (atomic slot alloc; order canonicalized in prep_k) ----
__global__ void bucket_k(const int* __restrict__ pair, int* __restrict__ deg,
                         int* __restrict__ eidb){
  int e = blockIdx.x*blockDim.x + threadIdx.x;
  if (e < NE){
    int v = pair[2*e];
    int pos = atomicAdd(&deg[v], 1);
    if (pos < SLOT) eidb[v*SLOT + pos] = e;
  }
}

// ---- canonical order via lane-parallel rank (edge ids unique) + resolve nbr ----
// wave per node: lane i<deg owns edge i; rank = #{j: id_j < id_i}; O(deg^2) broadcast reads
__global__ __launch_bounds__(512) void prep_k(const int* __restrict__ pair,
                       const int* __restrict__ deg,
                       const int* __restrict__ eidb, int2* __restrict__ enb){
  int w = threadIdx.x >> 6, lane = threadIdx.x & 63;
  int v = blockIdx.x * 8 + w;
  if (v >= NN) return;
  int dg = deg[v]; if (dg > SLOT) dg = SLOT;
  if (lane < dg){
    int e = eidb[v*SLOT + lane];
    int rank = 0;
    for (int j=0; j<dg; ++j){ int ej = eidb[v*SLOT + j]; rank += (ej < e); }
    enb[v*SLOT + rank] = make_int2(e, pair[2*e + 1]);
  }
}

// ---- fused step, 8-node tile, 8 waves: gather (1 wave/node) -> MFMA agg -> MFMA GRU ----
__global__ __launch_bounds__(512) void step_k(const float* __restrict__ h_in,
        float* __restrict__ h_out, const float* __restrict__ ef,
        const int* __restrict__ deg, const int2* __restrict__ enb,
        const _Float16* __restrict__ wb, const _Float16* __restrict__ gkt,
        const _Float16* __restrict__ rkt, const float* __restrict__ gb){
  __shared__ _Float16 Gs[NT*LDK];      // 17536 B
  __shared__ _Float16 aggT[NT*72];     // 1152 B
  __shared__ _Float16 hT[NT*72];       // 1152 B

  int tid = threadIdx.x;
  int w = tid >> 6, lane = tid & 63;
  int r16 = lane & 15, kh = lane >> 4;
  int vb = blockIdx.x * NT;
  int v  = vb + w;                     // this wave's node

  hT[w*72 + lane] = (_Float16)h_in[(size_t)v*64 + lane];

  // ---- gather: wave w owns node v (17 features, lane = unit) ----
  {
    int dgv = rfl(deg[v]); if (dgv > SLOT) dgv = SLOT;
    const int2* lst = enb + v*SLOT;
    float g[FEP];
    #pragma unroll
    for (int f=0;f<FEP;++f) g[f] = 0.f;
    for (int c0=0; c0<dgv; c0+=CH){
      int ee[CH], nb[CH];
      #pragma unroll
      for (int q=0;q<CH;++q){ int i=c0+q;
        if (i<dgv){ int2 p = lst[i]; ee[q]=rfl(p.x); nb[q]=rfl(p.y); }
        else { ee[q]=0; nb[q]=0; } }
      float hj[CH];
      #pragma unroll
      for (int q=0;q<CH;++q){ int i=c0+q;
        hj[q] = (i<dgv) ? h_in[(size_t)nb[q]*64 + lane] : 0.f; }
      #pragma unroll
      for (int q=0;q<CH;++q){ int i=c0+q;
        if (i<dgv){
          const float4* er = (const float4*)(ef + (size_t)ee[q]*FE);
          float4 e0 = er[0], e1 = er[1], e2 = er[2], e3 = er[3];
          g[ 0]=fmaf(e0.x,hj[q],g[ 0]); g[ 1]=fmaf(e0.y,hj[q],g[ 1]);
          g[ 2]=fmaf(e0.z,hj[q],g[ 2]); g[ 3]=fmaf(e0.w,hj[q],g[ 3]);
          g[ 4]=fmaf(e1.x,hj[q],g[ 4]); g[ 5]=fmaf(e1.y,hj[q],g[ 5]);
          g[ 6]=fmaf(e1.z,hj[q],g[ 6]); g[ 7]=fmaf(e1.w,hj[q],g[ 7]);
          g[ 8]=fmaf(e2.x,hj[q],g[ 8]); g[ 9]=fmaf(e2.y,hj[q],g[ 9]);
          g[10]=fmaf(e2.z,hj[q],g[10]); g[11]=fmaf(e2.w,hj[q],g[11]);
          g[12]=fmaf(e3.x,hj[q],g[12]); g[13]=fmaf(e3.y,hj[q],g[13]);
          g[14]=fmaf(e3.z,hj[q],g[14]); g[15]=fmaf(e3.w,hj[q],g[15]);
          g[16] += hj[q];
        } }
    }
    #pragma unroll
    for (int f=0;f<FEP;++f) Gs[w*LDK + f*64 + lane] = (_Float16)g[f];
  }
  __syncthreads();

  // ---- agg matmul: waves 0-3, wave w = cols w*16..w*16+15; A rows 0-7 valid ----
  if (w < 4){
    f32x4 acc = {0.f,0.f,0.f,0.f};
    const _Float16* ap = Gs + (r16 & 7)*LDK + kh*8;
    const _Float16* bp = wb + (size_t)(w*16 + r16)*KD + kh*8;
    #pragma unroll 4
    for (int k0=0; k0<KD; k0+=32){
      half8 a = *(const half8*)(ap + k0);
      half8 b = *(const half8*)(bp + k0);
      acc = __builtin_amdgcn_mfma_f32_16x16x32_f16(a, b, acc, 0, 0, 0);
    }
    if (kh < 2){           // C rows 0-7 live in kh 0,1 (row = kh*4+r)
      #pragma unroll
      for (int r=0;r<4;++r) aggT[(kh*4+r)*72 + w*16 + r16] = (_Float16)acc[r];
    }
  }
  __syncthreads();

  // ---- GRU via MFMA: waves 0-3, wave w owns units uw = w*16 + r16 ----
  if (w < 4){
    int uw = w*16 + r16;
    const _Float16* az = aggT + (r16 & 7)*72 + kh*8;
    const _Float16* ah = hT   + (r16 & 7)*72 + kh*8;
    f32x4 mxz={0.f,0.f,0.f,0.f}, mxr=mxz, mxh=mxz, mhz=mxz, mhr=mxz, mhh=mxz;
    #pragma unroll
    for (int ks=0; ks<2; ++ks){
      half8 aa = *(const half8*)(az + ks*32);
      half8 hh = *(const half8*)(ah + ks*32);
      half8 bz = *(const half8*)(gkt + (size_t)(      uw)*64 + ks*32 + kh*8);
      half8 br = *(const half8*)(gkt + (size_t)( 64 + uw)*64 + ks*32 + kh*8);
      half8 bh = *(const half8*)(gkt + (size_t)(128 + uw)*64 + ks*32 + kh*8);
      half8 cz = *(const half8*)(rkt + (size_t)(      uw)*64 + ks*32 + kh*8);
      half8 cr = *(const half8*)(rkt + (size_t)( 64 + uw)*64 + ks*32 + kh*8);
      half8 ch = *(const half8*)(rkt + (size_t)(128 + uw)*64 + ks*32 + kh*8);
      mxz = __builtin_amdgcn_mfma_f32_16x16x32_f16(aa, bz, mxz, 0,0,0);
      mxr = __builtin_amdgcn_mfma_f32_16x16x32_f16(aa, br, mxr, 0,0,0);
      mxh = __builtin_amdgcn_mfma_f32_16x16x32_f16(aa, bh, mxh, 0,0,0);
      mhz = __builtin_amdgcn_mfma_f32_16x16x32_f16(hh, cz, mhz, 0,0,0);
      mhr = __builtin_amdgcn_mfma_f32_16x16x32_f16(hh, cr, mhr, 0,0,0);
      mhh = __builtin_amdgcn_mfma_f32_16x16x32_f16(hh, ch, mhh, 0,0,0);
    }
    if (kh < 2){
      float b0z = gb[uw],      b0r = gb[64+uw],  b0h = gb[128+uw];
      float b1z = gb[192+uw],  b1r = gb[256+uw], b1h = gb[320+uw];
      #pragma unroll
      for (int r=0;r<4;++r){
        int row = vb + kh*4 + r;
        float z  = sigm(mxz[r] + b0z + mhz[r] + b1z);
        float rr = sigm(mxr[r] + b0r + mhr[r] + b1r);
        float hc = tanhf(mxh[r] + b0h + rr*(mhh[r] + b1h));
        float hold = h_in[(size_t)row*64 + uw];
        h_out[(size_t)row*64 + uw] = z*hold + (1.f - z)*hc;
      }
    }
  }
}

extern "C" void kernel_launch(void* const* d_in, const int* in_sizes, int n_in,
                              void* d_out, int out_size, void* d_ws, size_t ws_size,
                              hipStream_t stream){
  const float* nodef = (const float*)d_in[0];
  const float* edgef = (const float*)d_in[1];
  const int*   pair  = (const int*)  d_in[2];
  const float* ek    = (const float*)d_in[3];
  const float* ebias = (const float*)d_in[4];
  const float* gk    = (const float*)d_in[5];
  const float* rk    = (const float*)d_in[6];
  const float* gb    = (const float*)d_in[7];

  char* ws = (char*)d_ws;
  size_t o = 0;
  auto carve = [&](size_t bytes)->char*{
    char* p = ws + o; o = (o + bytes + 255) & ~255ULL; return p; };
  int*      deg  = (int*)     carve(NN*sizeof(int));
  int*      eidb = (int*)     carve((size_t)NN*SLOT*sizeof(int));
  int2*     enb  = (int2*)    carve((size_t)NN*SLOT*sizeof(int2));
  _Float16* wb   = (_Float16*)carve((size_t)WBN*sizeof(_Float16));
  _Float16* gkt  = (_Float16*)carve((size_t)GTN*sizeof(_Float16));
  _Float16* rkt  = (_Float16*)carve((size_t)GTN*sizeof(_Float16));
  float*    hA   = (float*)   carve((size_t)NN*UU*sizeof(float));
  float*    hB   = (float*)   carve((size_t)NN*UU*sizeof(float));

  build_k <<<(WBN+2*GTN+255)/256, 256, 0, stream>>>(ek, ebias, gk, rk, wb, gkt, rkt, deg);
  bucket_k<<<(NE+255)/256, 256, 0, stream>>>(pair, deg, eidb);
  prep_k  <<<NB, 512, 0, stream>>>(pair, deg, eidb, enb);

  const float* hin = nodef;
  for (int s=0; s<NSTEPS; ++s){
    float* hout = (s == NSTEPS-1) ? (float*)d_out : ((s & 1) ? hB : hA);
    step_k<<<NB, 512, 0, stream>>>(hin, hout, edgef, deg, enb,
                                   wb, gkt, rkt, gb);
    hin = hout;
  }
}